// Round 22
// baseline (41.362 us; speedup 1.0000x reference)
//
#include <hip/hip_runtime.h>
#include <math.h>

constexpr int TLEN = 512;
constexpr int CDIM = 64;
constexpr int BDIM = 2;

// Kernel 1: projections (R20, unchanged). hkt4 transposed + hqb row-major.
__global__ __launch_bounds__(256) void proj_kernel(
    const float* __restrict__ x, const float* __restrict__ pos,
    const float* __restrict__ W1, const float* __restrict__ b1,
    float4* __restrict__ hkt4, float* __restrict__ hqb)
{
    const int tid = threadIdx.x;
    const int r0g = blockIdx.x * 4;
    const int b   = r0g >> 9;
    const int t0  = r0g & (TLEN - 1);

    __shared__ float4 w1_s[64 * 64];          // 64 KiB swizzled W1 (Wk|Wq)
    __shared__ alignas(16) float x1s[4][128];
    __shared__ float hks[CDIM][5];            // +1 pad

    const float4* W1f4 = (const float4*)W1;
    #pragma unroll
    for (int m = tid; m < 64 * 64; m += 256) {
        const int c = m >> 6, e4 = m & 63;
        w1_s[c * 64 + (e4 ^ (c & 63))] = W1f4[c * 64 + e4];
    }
    #pragma unroll
    for (int e = tid; e < 4 * 128; e += 256) {
        const int r4 = e >> 7, d = e & 127;
        const int grow = r0g + r4;
        const int tt = grow & (TLEN - 1);
        x1s[r4][d] = (d < CDIM) ? pos[tt * CDIM + d]
                                : x[grow * CDIM + (d - CDIM)];
    }
    __syncthreads();

    {
        const int sub = tid >> 6, c = tid & 63;
        const int grow = r0g + sub;
        const float4* xv = (const float4*)x1s[sub];
        const float4* wb = w1_s + c * 64;
        const int sw = c & 63;
        float4 ak = make_float4(0.f, 0.f, 0.f, 0.f);
        float4 aq = ak;
        #pragma unroll
        for (int d4 = 0; d4 < 32; ++d4) {
            const float4 xx = xv[d4];
            const float4 wk = wb[d4 ^ sw];
            const float4 wq = wb[(32 + d4) ^ sw];
            ak.x = fmaf(xx.x, wk.x, ak.x); ak.y = fmaf(xx.y, wk.y, ak.y);
            ak.z = fmaf(xx.z, wk.z, ak.z); ak.w = fmaf(xx.w, wk.w, ak.w);
            aq.x = fmaf(xx.x, wq.x, aq.x); aq.y = fmaf(xx.y, wq.y, aq.y);
            aq.z = fmaf(xx.z, wq.z, aq.z); aq.w = fmaf(xx.w, wq.w, aq.w);
        }
        hks[c][sub] = (ak.x + ak.y) + (ak.z + ak.w);
        hqb[grow * CDIM + c] = (aq.x + aq.y) + (aq.z + aq.w) + b1[c];
    }
    __syncthreads();

    if (tid < 64) {                            // transpose-store f4 over c
        const int c4 = tid >> 2, tl = tid & 3;
        const float4 v = make_float4(hks[c4 * 4 + 0][tl], hks[c4 * 4 + 1][tl],
                                     hks[c4 * 4 + 2][tl], hks[c4 * 4 + 3][tl]);
        hkt4[(b * 16 + c4) * TLEN + t0 + tl] = v;
    }
}

// Kernel 2: attn, 256 blocks x 512 threads, 4 rows {p, p+128, 383-p, 511-p}.
// Score: kk loaded ONCE per c4, 4 rows updated unconditionally (R9 loop, no
// branches); exp masked by causality. PV: x loads shared across 4 rows.
// Per-CU L2-port bytes: 768KB -> 256KB vs R20.
__global__ __launch_bounds__(512, 4) void attn_kernel(
    const float* __restrict__ x,   const float* __restrict__ W2,
    const float* __restrict__ b2,  const float* __restrict__ Wv,
    const float4* __restrict__ hkt4, const float4* __restrict__ hqb4,
    float* __restrict__ out)
{
    const int tid = threadIdx.x;
    const int idx = blockIdx.x;               // 0..255
    const int b   = idx & 1;
    const int p   = idx >> 1;                 // 0..127
    int r[4];
    r[0] = p; r[1] = p + 128; r[2] = 383 - p; r[3] = 511 - p;  // ascending

    __shared__ float4 wv_s[64 * 16];          // 16 KiB swizzled Wv
    __shared__ float4 hq_s[4][16];            // hq+b1, 4 rows (from proj)
    __shared__ float4 w24_s[16];
    __shared__ alignas(16) float pS[4][TLEN];
    __shared__ float4 wreds4[8];              // per-wave exp-sums, 4 rows
    __shared__ float pvs[4][8][CDIM];
    __shared__ alignas(16) float o_s[4][CDIM];

    // ---- stage Wv (swizzled), hq rows, W2 ----
    const float4* Wvf4 = (const float4*)Wv;
    #pragma unroll
    for (int m = tid; m < 64 * 16; m += 512) {
        const int hh = m >> 4, e4 = m & 15;
        wv_s[hh * 16 + (e4 ^ (hh & 15))] = Wvf4[hh * 16 + e4];
    }
    if (tid < 64) {
        const int l = tid >> 4, e = tid & 15;
        hq_s[l][e] = hqb4[(b * TLEN + r[l]) * 16 + e];
    } else if (tid < 80) {
        w24_s[tid - 64] = ((const float4*)W2)[tid - 64];
    }
    __syncthreads();

    // ---- scores: one kk load feeds 4 rows (no branches in the loop) ----
    const float b2v = b2[0];
    const float4* hk4b = hkt4 + b * 16 * TLEN;
    const int j = tid;
    const int w = tid >> 6;

    float4 acc0 = make_float4(0.f, 0.f, 0.f, 0.f);
    float4 acc1 = acc0, acc2 = acc0, acc3 = acc0;
    #pragma unroll
    for (int c4 = 0; c4 < 16; ++c4) {
        const float4 kk = hk4b[c4 * TLEN + j];       // 16B/lane coalesced
        const float4 ww = w24_s[c4];                 // uniform LDS broadcast
        const float4 q0 = hq_s[0][c4];
        const float4 q1 = hq_s[1][c4];
        const float4 q2 = hq_s[2][c4];
        const float4 q3 = hq_s[3][c4];
        acc0.x = fmaf(fmaxf(kk.x + q0.x, 0.f), ww.x, acc0.x);
        acc0.y = fmaf(fmaxf(kk.y + q0.y, 0.f), ww.y, acc0.y);
        acc0.z = fmaf(fmaxf(kk.z + q0.z, 0.f), ww.z, acc0.z);
        acc0.w = fmaf(fmaxf(kk.w + q0.w, 0.f), ww.w, acc0.w);
        acc1.x = fmaf(fmaxf(kk.x + q1.x, 0.f), ww.x, acc1.x);
        acc1.y = fmaf(fmaxf(kk.y + q1.y, 0.f), ww.y, acc1.y);
        acc1.z = fmaf(fmaxf(kk.z + q1.z, 0.f), ww.z, acc1.z);
        acc1.w = fmaf(fmaxf(kk.w + q1.w, 0.f), ww.w, acc1.w);
        acc2.x = fmaf(fmaxf(kk.x + q2.x, 0.f), ww.x, acc2.x);
        acc2.y = fmaf(fmaxf(kk.y + q2.y, 0.f), ww.y, acc2.y);
        acc2.z = fmaf(fmaxf(kk.z + q2.z, 0.f), ww.z, acc2.z);
        acc2.w = fmaf(fmaxf(kk.w + q2.w, 0.f), ww.w, acc2.w);
        acc3.x = fmaf(fmaxf(kk.x + q3.x, 0.f), ww.x, acc3.x);
        acc3.y = fmaf(fmaxf(kk.y + q3.y, 0.f), ww.y, acc3.y);
        acc3.z = fmaf(fmaxf(kk.z + q3.z, 0.f), ww.z, acc3.z);
        acc3.w = fmaf(fmaxf(kk.w + q3.w, 0.f), ww.w, acc3.w);
    }
    float s[4];
    s[0] = (acc0.x + acc0.y) + (acc0.z + acc0.w);
    s[1] = (acc1.x + acc1.y) + (acc1.z + acc1.w);
    s[2] = (acc2.x + acc2.y) + (acc2.z + acc2.w);
    s[3] = (acc3.x + acc3.y) + (acc3.z + acc3.w);

    float sw4[4];
    #pragma unroll
    for (int k = 0; k < 4; ++k) {
        const float sv = (s[k] + b2v) * 0.125f;
        const float pt = (j <= r[k]) ? __expf(sv) : 0.f;  // bounded scores
        pS[k][j] = pt;
        float sm = pt;
        #pragma unroll
        for (int off = 32; off > 0; off >>= 1)
            sm += __shfl_xor(sm, off);
        sw4[k] = sm;
    }
    if ((tid & 63) == 0)
        wreds4[w] = make_float4(sw4[0], sw4[1], sw4[2], sw4[3]);
    __syncthreads();                           // pS + wreds visible

    // ---- PV (unnormalized): 4 rows share x loads; nested causal guards ----
    const int h = tid & 63;
    const int g = w;
    const float* xh = x + b * TLEN * CDIM + h;
    const int nj4 = (r[3] >> 2) + 1;
    float4 a0 = make_float4(0.f, 0.f, 0.f, 0.f);
    float4 a1 = a0, a2 = a0, a3 = a0;
    for (int j4 = g; j4 < nj4; j4 += 8) {
        const int j0 = j4 * 4;
        const float4 p3v = ((const float4*)pS[3])[j4];   // LDS broadcast
        const float x0 = xh[j0 * CDIM];                  // coalesced
        const float x1 = xh[(j0 + 1) * CDIM];
        const float x2 = xh[(j0 + 2) * CDIM];
        const float x3 = xh[(j0 + 3) * CDIM];
        a3.x = fmaf(p3v.x, x0, a3.x); a3.y = fmaf(p3v.y, x1, a3.y);
        a3.z = fmaf(p3v.z, x2, a3.z); a3.w = fmaf(p3v.w, x3, a3.w);
        if (j0 <= r[2]) {                                // wave-uniform
            const float4 pv = ((const float4*)pS[2])[j4];
            a2.x = fmaf(pv.x, x0, a2.x); a2.y = fmaf(pv.y, x1, a2.y);
            a2.z = fmaf(pv.z, x2, a2.z); a2.w = fmaf(pv.w, x3, a2.w);
        }
        if (j0 <= r[1]) {
            const float4 pv = ((const float4*)pS[1])[j4];
            a1.x = fmaf(pv.x, x0, a1.x); a1.y = fmaf(pv.y, x1, a1.y);
            a1.z = fmaf(pv.z, x2, a1.z); a1.w = fmaf(pv.w, x3, a1.w);
        }
        if (j0 <= r[0]) {
            const float4 pv = ((const float4*)pS[0])[j4];
            a0.x = fmaf(pv.x, x0, a0.x); a0.y = fmaf(pv.y, x1, a0.y);
            a0.z = fmaf(pv.z, x2, a0.z); a0.w = fmaf(pv.w, x3, a0.w);
        }
    }
    pvs[0][g][h] = (a0.x + a0.y) + (a0.z + a0.w);
    pvs[1][g][h] = (a1.x + a1.y) + (a1.z + a1.w);
    pvs[2][g][h] = (a2.x + a2.y) + (a2.z + a2.w);
    pvs[3][g][h] = (a3.x + a3.y) + (a3.z + a3.w);
    __syncthreads();
    if (tid < 256) {
        const int l = tid >> 6, hh = tid & 63;
        float o = pvs[l][0][hh];
        #pragma unroll
        for (int ww = 1; ww < 8; ++ww) o += pvs[l][ww][hh];
        float gsum = 0.f;
        #pragma unroll
        for (int ww = 0; ww < 8; ++ww) {
            const float4 rs = wreds4[ww];
            gsum += (l == 0) ? rs.x : (l == 1) ? rs.y : (l == 2) ? rs.z : rs.w;
        }
        o_s[l][hh] = o / gsum;                 // normalization folded here
    }
    __syncthreads();
    if (tid < 256) {                           // out = o_l . Wv[h,:] (LDS)
        const int l = tid >> 6, hh = tid & 63;
        const float4* wb = wv_s + hh * 16;
        const int sw = hh & 15;
        const float4* o4 = (const float4*)o_s[l];
        float4 a = make_float4(0.f, 0.f, 0.f, 0.f);
        #pragma unroll
        for (int c4 = 0; c4 < 16; ++c4) {
            const float4 wwv = wb[c4 ^ sw];
            const float4 oo = o4[c4];
            a.x = fmaf(oo.x, wwv.x, a.x); a.y = fmaf(oo.y, wwv.y, a.y);
            a.z = fmaf(oo.z, wwv.z, a.z); a.w = fmaf(oo.w, wwv.w, a.w);
        }
        out[(b * TLEN + r[l]) * CDIM + hh] = (a.x + a.y) + (a.z + a.w);
    }
}

extern "C" void kernel_launch(void* const* d_in, const int* in_sizes, int n_in,
                              void* d_out, int out_size, void* d_ws, size_t ws_size,
                              hipStream_t stream)
{
    const float* x   = (const float*)d_in[0];
    const float* pos = (const float*)d_in[1];
    const float* W1  = (const float*)d_in[2];
    const float* b1  = (const float*)d_in[3];
    const float* W2  = (const float*)d_in[4];
    const float* b2  = (const float*)d_in[5];
    const float* Wv  = (const float*)d_in[6];
    float* out = (float*)d_out;

    float4* hkt4 = (float4*)d_ws;                      // 256 KiB transposed hk
    float*  hqb  = (float*)d_ws + 4 * 16384;           // 256 KiB hq + b1

    proj_kernel<<<BDIM * TLEN / 4, 256, 0, stream>>>(x, pos, W1, b1, hkt4, hqb);
    attn_kernel<<<BDIM * TLEN / 4, 512, 0, stream>>>(x, W2, b2, Wv,
                                                     hkt4, (const float4*)hqb,
                                                     out);
}

// Round 23
// 18.692 us; speedup vs baseline: 2.2128x; 2.2128x over previous
//
#include <hip/hip_runtime.h>
#include <math.h>

constexpr int TLEN = 512;
constexpr int CDIM = 64;
constexpr int BDIM = 2;

// Kernel 1: projections. Outputs:
//   hkt4[(b*16+c4)*512 + t] : hk transposed, f4-over-c
//   hqb[(b*512+t)*64 + c]   : hq + b1, row-major
// 256 blocks x 256 threads, 4 rows/block; full W1 (64 KB) staged swizzled.
__global__ __launch_bounds__(256) void proj_kernel(
    const float* __restrict__ x, const float* __restrict__ pos,
    const float* __restrict__ W1, const float* __restrict__ b1,
    float4* __restrict__ hkt4, float* __restrict__ hqb)
{
    const int tid = threadIdx.x;
    const int r0g = blockIdx.x * 4;
    const int b   = r0g >> 9;
    const int t0  = r0g & (TLEN - 1);

    __shared__ float4 w1_s[64 * 64];          // 64 KiB swizzled W1 (Wk|Wq)
    __shared__ alignas(16) float x1s[4][128];
    __shared__ float hks[CDIM][5];            // +1 pad

    const float4* W1f4 = (const float4*)W1;
    #pragma unroll
    for (int m = tid; m < 64 * 64; m += 256) {
        const int c = m >> 6, e4 = m & 63;
        w1_s[c * 64 + (e4 ^ (c & 63))] = W1f4[c * 64 + e4];
    }
    #pragma unroll
    for (int e = tid; e < 4 * 128; e += 256) {
        const int r4 = e >> 7, d = e & 127;
        const int grow = r0g + r4;
        const int tt = grow & (TLEN - 1);
        x1s[r4][d] = (d < CDIM) ? pos[tt * CDIM + d]
                                : x[grow * CDIM + (d - CDIM)];
    }
    __syncthreads();

    {
        const int sub = tid >> 6, c = tid & 63;
        const int grow = r0g + sub;
        const float4* xv = (const float4*)x1s[sub];
        const float4* wb = w1_s + c * 64;
        const int sw = c & 63;
        float4 ak = make_float4(0.f, 0.f, 0.f, 0.f);
        float4 aq = ak;
        #pragma unroll
        for (int d4 = 0; d4 < 32; ++d4) {
            const float4 xx = xv[d4];
            const float4 wk = wb[d4 ^ sw];
            const float4 wq = wb[(32 + d4) ^ sw];
            ak.x = fmaf(xx.x, wk.x, ak.x); ak.y = fmaf(xx.y, wk.y, ak.y);
            ak.z = fmaf(xx.z, wk.z, ak.z); ak.w = fmaf(xx.w, wk.w, ak.w);
            aq.x = fmaf(xx.x, wq.x, aq.x); aq.y = fmaf(xx.y, wq.y, aq.y);
            aq.z = fmaf(xx.z, wq.z, aq.z); aq.w = fmaf(xx.w, wq.w, aq.w);
        }
        hks[c][sub] = (ak.x + ak.y) + (ak.z + ak.w);
        hqb[grow * CDIM + c] = (aq.x + aq.y) + (aq.z + aq.w) + b1[c];
    }
    __syncthreads();

    if (tid < 64) {                            // transpose-store f4 over c
        const int c4 = tid >> 2, tl = tid & 3;
        const float4 v = make_float4(hks[c4 * 4 + 0][tl], hks[c4 * 4 + 1][tl],
                                     hks[c4 * 4 + 2][tl], hks[c4 * 4 + 3][tl]);
        hkt4[(b * 16 + c4) * TLEN + t0 + tl] = v;
    }
}

// Kernel 2: attn. 512 blocks x 512 threads, rows {p, 511-p}. Two-pass score
// (wave-uniform causal skip), no-max softmax (one barrier), shared-x PV,
// normalization in epilogue, Wv epilogue from swizzled LDS.
__global__ __launch_bounds__(512, 4) void attn_kernel(
    const float* __restrict__ x,   const float* __restrict__ W2,
    const float* __restrict__ b2,  const float* __restrict__ Wv,
    const float4* __restrict__ hkt4, const float4* __restrict__ hqb4,
    float* __restrict__ out)
{
    const int tid = threadIdx.x;
    const int idx = blockIdx.x;               // 0..511
    const int b   = idx & 1;
    const int p   = idx >> 1;                 // 0..255
    int rr[2];
    rr[0] = p; rr[1] = (TLEN - 1) - p;        // rr[1] >= 256 > rr[0]

    __shared__ float4 wv_s[64 * 16];          // 16 KiB swizzled Wv
    __shared__ float4 hq_s[2][16];            // hq+b1 both rows (from proj)
    __shared__ float4 w24_s[16];
    __shared__ alignas(16) float pS[2][TLEN];
    __shared__ float2 wreds[8];               // per-wave exp-sums (2 rows)
    __shared__ float pvs[2][8][CDIM];
    __shared__ alignas(16) float o_s[2][CDIM];

    // ---- stage Wv (swizzled), hq rows, W2 ----
    const float4* Wvf4 = (const float4*)Wv;
    #pragma unroll
    for (int m = tid; m < 64 * 16; m += 512) {
        const int hh = m >> 4, e4 = m & 15;
        wv_s[hh * 16 + (e4 ^ (hh & 15))] = Wvf4[hh * 16 + e4];
    }
    if (tid < 32) {
        const int rp = tid >> 4, e = tid & 15;
        hq_s[rp][e] = hqb4[(b * TLEN + rr[rp]) * 16 + e];
    } else if (tid < 48) {
        w24_s[tid - 32] = ((const float4*)W2)[tid - 32];
    }
    __syncthreads();

    // ---- scores -> exp -> pS + per-wave sums (two-pass, no max) ----
    const float b2v = b2[0];
    const float4* hk4b = hkt4 + b * 16 * TLEN;
    const int j = tid;
    const int w = tid >> 6;

    float swv[2];
    #pragma unroll
    for (int k = 0; k < 2; ++k) {
        const int rk = rr[k];
        if ((w << 6) <= rk) {                 // wave-uniform causal skip
            const float4* hq4 = hq_s[k];
            float4 acc = make_float4(0.f, 0.f, 0.f, 0.f);
            #pragma unroll
            for (int c4 = 0; c4 < 16; ++c4) {
                const float4 kk = hk4b[c4 * TLEN + j];
                const float4 qq = hq4[c4];
                const float4 w2v = w24_s[c4];
                acc.x = fmaf(fmaxf(kk.x + qq.x, 0.f), w2v.x, acc.x);
                acc.y = fmaf(fmaxf(kk.y + qq.y, 0.f), w2v.y, acc.y);
                acc.z = fmaf(fmaxf(kk.z + qq.z, 0.f), w2v.z, acc.z);
                acc.w = fmaf(fmaxf(kk.w + qq.w, 0.f), w2v.w, acc.w);
            }
            const bool vld = (j <= rk);
            const float sv = ((acc.x + acc.y) + (acc.z + acc.w) + b2v) * 0.125f;
            const float pt = vld ? __expf(sv) : 0.f;   // bounded scores
            pS[k][j] = pt;
            float sm = pt;
            #pragma unroll
            for (int off = 32; off > 0; off >>= 1)
                sm += __shfl_xor(sm, off);
            swv[k] = sm;
        } else {
            swv[k] = 0.f;                     // pS beyond rk never read
        }
    }
    if ((tid & 63) == 0) wreds[w] = make_float2(swv[0], swv[1]);
    __syncthreads();                           // pS + wreds visible

    // ---- PV (unnormalized), shared x loads, row-0 wave-uniform skip ----
    const int h = tid & 63;
    const int g = w;
    const float* xh = x + b * TLEN * CDIM + h;
    const int nj4 = (rr[1] >> 2) + 1;
    float4 a0 = make_float4(0.f, 0.f, 0.f, 0.f);
    float4 a1 = a0;
    for (int j4 = g; j4 < nj4; j4 += 8) {
        const int j0 = j4 * 4;
        const float4 p1v = ((const float4*)pS[1])[j4];  // LDS broadcast
        const float x0 = xh[j0 * CDIM];                 // coalesced
        const float x1 = xh[(j0 + 1) * CDIM];
        const float x2 = xh[(j0 + 2) * CDIM];
        const float x3 = xh[(j0 + 3) * CDIM];
        a1.x = fmaf(p1v.x, x0, a1.x); a1.y = fmaf(p1v.y, x1, a1.y);
        a1.z = fmaf(p1v.z, x2, a1.z); a1.w = fmaf(p1v.w, x3, a1.w);
        if (j0 <= rr[0]) {                              // wave-uniform
            const float4 p0v = ((const float4*)pS[0])[j4];
            a0.x = fmaf(p0v.x, x0, a0.x); a0.y = fmaf(p0v.y, x1, a0.y);
            a0.z = fmaf(p0v.z, x2, a0.z); a0.w = fmaf(p0v.w, x3, a0.w);
        }
    }
    pvs[0][g][h] = (a0.x + a0.y) + (a0.z + a0.w);
    pvs[1][g][h] = (a1.x + a1.y) + (a1.z + a1.w);
    __syncthreads();
    if (tid < 128) {
        const int k = tid >> 6, hh = tid & 63;
        float o = pvs[k][0][hh];
        #pragma unroll
        for (int ww = 1; ww < 8; ++ww) o += pvs[k][ww][hh];
        float gsum = 0.f;
        #pragma unroll
        for (int ww = 0; ww < 8; ++ww)
            gsum += (k == 0) ? wreds[ww].x : wreds[ww].y;
        o_s[k][hh] = o / gsum;                 // normalization folded here
    }
    __syncthreads();
    if (tid < 128) {                           // out = o_k . Wv[h,:] (LDS)
        const int k = tid >> 6, hh = tid & 63;
        const float4* wb = wv_s + hh * 16;
        const int sw = hh & 15;
        const float4* o4 = (const float4*)o_s[k];
        float4 a = make_float4(0.f, 0.f, 0.f, 0.f);
        #pragma unroll
        for (int c4 = 0; c4 < 16; ++c4) {
            const float4 wwv = wb[c4 ^ sw];
            const float4 oo = o4[c4];
            a.x = fmaf(oo.x, wwv.x, a.x); a.y = fmaf(oo.y, wwv.y, a.y);
            a.z = fmaf(oo.z, wwv.z, a.z); a.w = fmaf(oo.w, wwv.w, a.w);
        }
        out[(b * TLEN + rr[k]) * CDIM + hh] = (a.x + a.y) + (a.z + a.w);
    }
}

extern "C" void kernel_launch(void* const* d_in, const int* in_sizes, int n_in,
                              void* d_out, int out_size, void* d_ws, size_t ws_size,
                              hipStream_t stream)
{
    const float* x   = (const float*)d_in[0];
    const float* pos = (const float*)d_in[1];
    const float* W1  = (const float*)d_in[2];
    const float* b1  = (const float*)d_in[3];
    const float* W2  = (const float*)d_in[4];
    const float* b2  = (const float*)d_in[5];
    const float* Wv  = (const float*)d_in[6];
    float* out = (float*)d_out;

    float4* hkt4 = (float4*)d_ws;                      // 256 KiB transposed hk
    float*  hqb  = (float*)d_ws + 4 * 16384;           // 256 KiB hq + b1

    proj_kernel<<<BDIM * TLEN / 4, 256, 0, stream>>>(x, pos, W1, b1, hkt4, hqb);
    attn_kernel<<<BDIM * TLEN / 2, 512, 0, stream>>>(x, W2, b2, Wv,
                                                     hkt4, (const float4*)hqb,
                                                     out);
}